// Round 6
// baseline (493.556 us; speedup 1.0000x reference)
//
#include <hip/hip_runtime.h>
#include <hip/hip_cooperative_groups.h>
#include <stdint.h>

namespace cg = cooperative_groups;

#define OUT_F   2048
#define IN_BASE 2048
#define N_EMB   64
#define IN_TOT  2176   // 2048 + 128
#define NNZ_W   400000
#define NNZ_B   1024
#define BATCH   8192

typedef __bf16 bf16x8 __attribute__((ext_vector_type(8)));
typedef __bf16 bf16x4 __attribute__((ext_vector_type(4)));
typedef float  floatx16 __attribute__((ext_vector_type(16)));

#define AS1 __attribute__((address_space(1)))
#define AS3 __attribute__((address_space(3)))

// ---------------------------------------------------------------------------
// Single cooperative kernel: 256 blocks x 512 threads (1 block/CU, same
// occupancy the gemm already had), grid.sync() between phases.
//   P1: build_x (32 rows/block) + COO binning (segments grid-strided) + bias
//   P2: per-bin accumulate (block b = bin b) -> bf16 W (no W memset needed)
//   P3: 256x256 GEMM (flattened tile index), unchanged verified code
// Rationale (round-5 post-mortem): residue ~137us was invariant across five
// structurally different prep implementations while device-work arithmetic
// bounds prep at ~35us => the sink is per-kernel boundaries (launch gaps,
// tail drains, memset node).  Fusing deletes the boundaries and surfaces the
// whole pipeline as ONE top-1 dispatch with readable counters.
// ---------------------------------------------------------------------------
#define NSEG     391                                // ceil(400000/1024)
#define SEG_NNZ  1024                               // nnz per segment
#define CAP      24                                 // entries per (seg,bin)
#define NBIN     256                                // bins = row>>3
#define BIN_ELEMS (8 * IN_TOT)                      // 17408 floats per slice

#define BM 256
#define BN 256
#define BK 64
#define NKT (IN_TOT / BK)   // 34 K-tiles, 17 iterations of 2
static_assert(NKT % 2 == 0, "pipeline consumes K-tiles in pairs");

#define CFENCE asm volatile("" ::: "memory")
#define BAR do { CFENCE; __builtin_amdgcn_s_barrier(); CFENCE; } while (0)
#define VMW(n) asm volatile("s_waitcnt vmcnt(" #n ")" ::: "memory")
#define NOPS do {} while (0)

#define STAGE(G, SBC, buf, tile, half) do {                                     \
    const __bf16* _s = (G) + (size_t)((half) * 128) * IN_TOT + (tile) * 64;     \
    char* _d = (SBC) + (buf) * 32768 + (half) * 16384 + tid * 16;               \
    __builtin_amdgcn_global_load_lds((AS1 void*)(uintptr_t)_s,                  \
                                     (AS3 void*)_d, 16, 0, 0);                  \
    __builtin_amdgcn_global_load_lds((AS1 void*)(uintptr_t)(_s + (size_t)64 * IN_TOT), \
                                     (AS3 void*)(_d + 8192), 16, 0, 0);         \
} while (0)

#define RD_A(pA, mq) do {                                                       \
    _Pragma("unroll") for (int ks = 0; ks < 4; ks++) {                          \
        const int kc = ks * 2 + khalf;                                          \
        _Pragma("unroll") for (int mi = 0; mi < 2; mi++) {                      \
            const int r = (mq) * 128 + wm * 64 + mi * 32 + l32;                 \
            a[mi * 4 + ks] = *(const bf16x8*)((pA) + r * 64 + ((kc ^ (r & 7)) * 8)); \
        }                                                                       \
    }                                                                           \
} while (0)

#define RD_B(pB, nq, barr) do {                                                 \
    _Pragma("unroll") for (int ks = 0; ks < 4; ks++) {                          \
        const int kc = ks * 2 + khalf;                                          \
        const int rb = (nq) * 128 + wn * 32 + l32;                              \
        barr[ks] = *(const bf16x8*)((pB) + rb * 64 + ((kc ^ (rb & 7)) * 8));    \
    }                                                                           \
} while (0)

#define MMPH(mq, nq, barr) do {                                                 \
    BAR;                                                                        \
    __builtin_amdgcn_s_setprio(1);                                              \
    _Pragma("unroll") for (int mi = 0; mi < 2; mi++)                            \
        _Pragma("unroll") for (int ks = 0; ks < 4; ks++)                        \
            acc[mq][mi][nq] = __builtin_amdgcn_mfma_f32_32x32x16_bf16(          \
                a[mi * 4 + ks], barr[ks], acc[mq][mi][nq], 0, 0, 0);            \
    __builtin_amdgcn_s_setprio(0);                                              \
    BAR;                                                                        \
} while (0)

#define KTILE(buf, STG1, STG2, STG3, STG4, W4) do {                             \
    const __bf16* _pA = sA + (buf) * 16384;                                     \
    const __bf16* _pB = sB + (buf) * 16384;                                     \
    RD_A(_pA, 0); RD_B(_pB, 0, b0);                                             \
    STG1;              MMPH(0, 0, b0);                                          \
    RD_B(_pB, 1, b1);                                                           \
    STG2;              MMPH(0, 1, b1);                                          \
    RD_A(_pA, 1);                                                               \
    STG3;              MMPH(1, 1, b1);                                          \
    STG4; W4;          MMPH(1, 0, b0);                                          \
} while (0)

__global__ void __launch_bounds__(512, 2) fused_kernel(
    const float* __restrict__ x,
    const float* __restrict__ e0v, const int* __restrict__ e0p,
    const float* __restrict__ e1v, const int* __restrict__ e1p,
    const float* __restrict__ wv, const int* __restrict__ wr,
    const int* __restrict__ wc,
    const float* __restrict__ bv, const int* __restrict__ bi,
    __bf16* __restrict__ xb,
    float* __restrict__ segv, unsigned short* __restrict__ segm,
    unsigned char* __restrict__ segc,
    float* __restrict__ bfp,
    __bf16* __restrict__ Wb,
    float* __restrict__ C)
{
    __shared__ __align__(16) char smem[131072];     // union across phases
    const int tid = threadIdx.x;
    const int blk = blockIdx.x;                     // 0..255
    cg::grid_group grid = cg::this_grid();

    // ================= Phase 1: build_x + binning + bias =================
    {
        // ---- COO binning: segments grid-strided (uses smem as hist) ----
        unsigned int* hist = (unsigned int*)smem;
        for (int s = blk; s < NSEG; s += 256) {
            if (tid < NBIN) hist[tid] = 0;
            __syncthreads();
#pragma unroll
            for (int r = 0; r < 2; r++) {
                const int i = s * SEG_NNZ + r * 512 + tid;
                if (i < NNZ_W) {
                    const int row = wr[i], col = wc[i];
                    const int bin = row >> 3;
                    const unsigned int rank = atomicAdd(&hist[bin], 1u);
                    if (rank < CAP) {  // overflow prob ~1e-9 (Poisson(4))
                        const int p = (s * NBIN + bin) * CAP + (int)rank;
                        segv[p] = wv[i];
                        segm[p] = (unsigned short)((row & 7) * IN_TOT + col);
                    }
                }
            }
            __syncthreads();
            if (tid < NBIN)
                segc[s * NBIN + tid] =
                    (unsigned char)(hist[tid] < CAP ? hist[tid] : CAP);
            __syncthreads();   // hist reused next segment
        }

        // ---- bias scatter: blocks 0..1 (bfp pre-zeroed by memset) ----
        const int gbi = blk * 512 + tid;
        if (gbi < NNZ_B) unsafeAtomicAdd(bfp + bi[gbi], bv[gbi]);

        // ---- build_x: 32 rows per block ----
        for (int b = blk; b < BATCH; b += 256) {
            const float* xr = x + (size_t)b * IN_BASE;
            __bf16* xo = xb + (size_t)b * IN_TOT;
            {   // cols 0..2047
                const float4 t = *(const float4*)(xr + tid * 4);
                bf16x4 o;
                o[0] = (__bf16)t.x; o[1] = (__bf16)t.y;
                o[2] = (__bf16)t.z; o[3] = (__bf16)t.w;
                *(bf16x4*)(xo + tid * 4) = o;
            }
            if (tid < 32) {      // cols 2048..2175 (embeds)
                const int g = 512 + tid;
                float v[4];
                if (g < 528) {                       // embed0
                    const int j = (g - 512) * 4;
#pragma unroll
                    for (int t = 0; t < 4; t++) v[t] = e0v[j + t] * xr[e0p[j + t]];
                } else {                             // embed1
                    const int j = (g - 528) * 4;
#pragma unroll
                    for (int t = 0; t < 4; t++) {
                        const int p = e1p[j + t];
                        const float base = (p < IN_BASE)
                            ? xr[p]
                            : e0v[p - IN_BASE] * xr[e0p[p - IN_BASE]];
                        v[t] = e1v[j + t] * base;
                    }
                }
                bf16x4 o;
                o[0] = (__bf16)v[0]; o[1] = (__bf16)v[1];
                o[2] = (__bf16)v[2]; o[3] = (__bf16)v[3];
                *(bf16x4*)(xo + g * 4) = o;
            }
        }
    }
    __threadfence();
    grid.sync();

    // ================= Phase 2: per-bin accumulate -> bf16 W =============
    {
        float* Ws = (float*)smem;                   // 69,632 B
        const int b = blk;                          // bin 0..255
        for (int e = tid; e < BIN_ELEMS; e += 512) Ws[e] = 0.f;
        __syncthreads();
        for (int s = tid; s < NSEG; s += 512) {     // threads 0..390 active
            const int c    = segc[s * NBIN + b];
            const int base = (s * NBIN + b) * CAP;
            for (int j = 0; j < c; j++)
                atomicAdd(&Ws[segm[base + j]], segv[base + j]);
        }
        __syncthreads();
        __bf16* wo = Wb + (size_t)b * BIN_ELEMS;
        for (int e = tid; e < BIN_ELEMS / 4; e += 512) {
            bf16x4 o;
            o[0] = (__bf16)Ws[e * 4 + 0]; o[1] = (__bf16)Ws[e * 4 + 1];
            o[2] = (__bf16)Ws[e * 4 + 2]; o[3] = (__bf16)Ws[e * 4 + 3];
            *(bf16x4*)(wo + e * 4) = o;
        }
    }
    __threadfence();
    grid.sync();

    // ================= Phase 3: GEMM (unchanged verified code) ===========
    {
        __bf16* sA = (__bf16*)smem;                 // 64 KiB (2 bufs)
        __bf16* sB = (__bf16*)(smem + 65536);       // 64 KiB
        const __bf16* A = xb;
        const __bf16* W = Wb;
        const float*  bias = bfp;

        const int bm    = blk & 31;      // M tile (32)
        const int bn    = blk >> 5;      // N tile (8)
        const int wave  = tid >> 6;
        const int lane  = tid & 63;
        const int wm    = wave >> 2;     // 0..1
        const int wn    = wave & 3;      // 0..3
        const int l32   = lane & 31;
        const int khalf = lane >> 5;

        floatx16 acc[2][2][2] = {};      // [m quad][mi][n quad]
        bf16x8 a[8];                     // A-frag cache
        bf16x8 b0[4], b1[4];             // B-frag caches

        const int srow   = tid >> 3;
        const int kchunk = ((tid & 7) ^ ((tid >> 3) & 7)) * 8;
        const __bf16* Ag = A + (size_t)(bm * BM + srow) * IN_TOT + kchunk;
        const __bf16* Wg = W + (size_t)(bn * BN + srow) * IN_TOT + kchunk;
        char* sAc = (char*)sA;
        char* sBc = (char*)sB;

        STAGE(Ag, sAc, 0, 0, 0);
        STAGE(Ag, sAc, 0, 0, 1);
        STAGE(Wg, sBc, 0, 0, 0);
        STAGE(Wg, sBc, 0, 0, 1);
        STAGE(Ag, sAc, 1, 1, 0);
        STAGE(Wg, sBc, 1, 1, 1);
        VMW(4);
        BAR;

#pragma unroll 1
        for (int i = 0; i < NKT / 2 - 1; ++i) {
            const int t1 = 2 * i + 1, t2 = 2 * i + 2, t3 = 2 * i + 3;
            KTILE(0, STAGE(Ag, sAc, 1, t1, 1), STAGE(Wg, sBc, 1, t1, 0),
                     STAGE(Ag, sAc, 0, t2, 0), STAGE(Wg, sBc, 0, t2, 1), VMW(4));
            KTILE(1, STAGE(Ag, sAc, 0, t2, 1), STAGE(Wg, sBc, 0, t2, 0),
                     STAGE(Ag, sAc, 1, t3, 0), STAGE(Wg, sBc, 1, t3, 1), VMW(4));
        }
        KTILE(0, STAGE(Ag, sAc, 1, NKT - 1, 1), STAGE(Wg, sBc, 1, NKT - 1, 0),
                 NOPS, NOPS, VMW(0));
        KTILE(1, NOPS, NOPS, NOPS, NOPS, NOPS);

        // epilogue: C/D col = lane&31, row = (reg&3)+8*(reg>>2)+4*khalf
#pragma unroll
        for (int m = 0; m < 2; m++)
#pragma unroll
        for (int mi = 0; mi < 2; mi++)
#pragma unroll
        for (int n = 0; n < 2; n++) {
            const int colg = bn * BN + n * 128 + wn * 32 + l32;
            const float bvv = bias[colg];
            const int rowb = bm * BM + m * 128 + wm * 64 + mi * 32 + 4 * khalf;
#pragma unroll
            for (int reg = 0; reg < 16; reg++) {
                const int rowg = rowb + (reg & 3) + 8 * (reg >> 2);
                C[(size_t)rowg * OUT_F + colg] = acc[m][mi][n][reg] + bvv;
            }
        }
    }
}

// ---------------------------------------------------------------------------
// Launch
// ---------------------------------------------------------------------------
extern "C" void kernel_launch(void* const* d_in, const int* in_sizes, int n_in,
                              void* d_out, int out_size, void* d_ws, size_t ws_size,
                              hipStream_t stream) {
    const float* x      = (const float*)d_in[0];
    const float* w_vals = (const float*)d_in[1];
    const int*   w_rows = (const int*)  d_in[2];
    const int*   w_cols = (const int*)  d_in[3];
    const float* b_vals = (const float*)d_in[4];
    const int*   b_idx  = (const int*)  d_in[5];
    const float* e0v    = (const float*)d_in[6];
    const int*   e0p    = (const int*)  d_in[7];
    const float* e1v    = (const float*)d_in[8];
    const int*   e1p    = (const int*)  d_in[9];
    float* out = (float*)d_out;

    // workspace: Wb | bfp | xb | segv | segm | segc   (~59.1 MB)
    char* ws = (char*)d_ws;
    const size_t W_BF16_BYTES = (size_t)OUT_F * IN_TOT * 2;      //  8,912,896
    const size_t B_F32_BYTES  = (size_t)OUT_F * 4;               //      8,192
    const size_t XB_BYTES     = (size_t)BATCH * IN_TOT * 2;      // 35,651,584
    const size_t SEGV_BYTES   = (size_t)NSEG * NBIN * CAP * 4;   //  9,609,216
    const size_t SEGM_BYTES   = (size_t)NSEG * NBIN * CAP * 2;   //  4,804,608
    __bf16*         Wb   = (__bf16*)ws;
    float*          bfp  = (float*)(ws + W_BF16_BYTES);
    __bf16*         xb   = (__bf16*)(ws + W_BF16_BYTES + B_F32_BYTES);
    float*          segv = (float*)(ws + W_BF16_BYTES + B_F32_BYTES + XB_BYTES);
    unsigned short* segm = (unsigned short*)((char*)segv + SEGV_BYTES);
    unsigned char*  segc = (unsigned char*)((char*)segm + SEGM_BYTES);

    // only the bias accumulator needs zeroing (8 KB)
    hipMemsetAsync(bfp, 0, B_F32_BYTES, stream);

    void* args[] = {
        (void*)&x, (void*)&e0v, (void*)&e0p, (void*)&e1v, (void*)&e1p,
        (void*)&w_vals, (void*)&w_rows, (void*)&w_cols,
        (void*)&b_vals, (void*)&b_idx,
        (void*)&xb, (void*)&segv, (void*)&segm, (void*)&segc,
        (void*)&bfp, (void*)&Wb, (void*)&out
    };
    hipLaunchCooperativeKernel((const void*)fused_kernel,
                               dim3(256), dim3(512), args, 0, stream);
}

// Round 7
// 212.496 us; speedup vs baseline: 2.3227x; 2.3227x over previous
//
#include <hip/hip_runtime.h>
#include <stdint.h>

#define OUT_F   2048
#define IN_BASE 2048
#define N_EMB   64
#define IN_TOT  2176   // 2048 + 128
#define NNZ_W   400000
#define NNZ_B   1024
#define BATCH   8192

typedef __bf16 bf16x8 __attribute__((ext_vector_type(8)));
typedef __bf16 bf16x4 __attribute__((ext_vector_type(4)));
typedef float  floatx16 __attribute__((ext_vector_type(16)));

#define AS1 __attribute__((address_space(1)))
#define AS3 __attribute__((address_space(3)))

// ---------------------------------------------------------------------------
// Kernel 1: build_x + COO binning + bias (r5 structure, verified; prep+accum
// measured ~8us combined via r5/r6 simultaneous accounting).  Round-6 lesson:
// do NOT fuse these with the GEMM — 1 block/CU occupancy starves the
// streaming/gather phases (370us fused vs ~89us as separate kernels).
// ---------------------------------------------------------------------------
#define NSEG     391                                // ceil(400000/1024)
#define SEG_NNZ  1024                               // nnz per pass-A block
#define CAP      24                                 // entries per (block,bin)
#define NBIN     256                                // bins = row>>3
#define BIN_ELEMS (8 * IN_TOT)                      // 17408 floats per slice

#define NB_SCAT  NSEG                               // blocks 0..390
#define NB_BIAS  2                                  // blocks 391..392
#define NB_BUILD BATCH                              // blocks 393..8584

__global__ void __launch_bounds__(512) prep_kernel(
    const float* __restrict__ x,
    const float* __restrict__ e0v, const int* __restrict__ e0p,
    const float* __restrict__ e1v, const int* __restrict__ e1p,
    __bf16* __restrict__ xb,
    const float* __restrict__ wv, const int* __restrict__ wr,
    const int* __restrict__ wc,
    const float* __restrict__ bv, const int* __restrict__ bi,
    float* __restrict__ segv, unsigned short* __restrict__ segm,
    unsigned char* __restrict__ segc,
    float* __restrict__ bfp)
{
    const int tid = threadIdx.x;
    const int blk = blockIdx.x;

    if (blk < NB_SCAT) {
        // ---- bin 1024 nnz by row>>3 into private segments ----
        __shared__ unsigned int hist[NBIN];
        if (tid < NBIN) hist[tid] = 0;
        __syncthreads();
#pragma unroll
        for (int r = 0; r < 2; r++) {
            const int i = blk * SEG_NNZ + r * 512 + tid;
            if (i < NNZ_W) {
                const int row = wr[i], col = wc[i];
                const int bin = row >> 3;
                const unsigned int rank = atomicAdd(&hist[bin], 1u);
                if (rank < CAP) {   // overflow prob ~1e-9 (Poisson(4) tail)
                    const int p = (blk * NBIN + bin) * CAP + (int)rank;
                    segv[p] = wv[i];
                    segm[p] = (unsigned short)((row & 7) * IN_TOT + col);
                }
            }
        }
        __syncthreads();
        if (tid < NBIN)
            segc[blk * NBIN + tid] =
                (unsigned char)(hist[tid] < CAP ? hist[tid] : CAP);
    } else if (blk < NB_SCAT + NB_BIAS) {
        const int i = (blk - NB_SCAT) * 512 + tid;
        if (i < NNZ_B) unsafeAtomicAdd(bfp + bi[i], bv[i]);
    } else {
        // ---- build_x: one row per block, 512 threads ----
        const int b = blk - NB_SCAT - NB_BIAS;
        const float* xr = x + (size_t)b * IN_BASE;
        __bf16* xo = xb + (size_t)b * IN_TOT;

        {   // cols 0..2047: straight cast, 512 threads x 4 elems
            const float4 t = *(const float4*)(xr + tid * 4);
            bf16x4 o;
            o[0] = (__bf16)t.x; o[1] = (__bf16)t.y;
            o[2] = (__bf16)t.z; o[3] = (__bf16)t.w;
            *(bf16x4*)(xo + tid * 4) = o;
        }
        if (tid < 32) {      // cols 2048..2175 (embeds)
            const int g = 512 + tid;
            float v[4];
            if (g < 528) {                             // embed0: cols 2048..2111
                const int j = (g - 512) * 4;
#pragma unroll
                for (int t = 0; t < 4; t++) v[t] = e0v[j + t] * xr[e0p[j + t]];
            } else {                                   // embed1: cols 2112..2175
                const int j = (g - 528) * 4;
#pragma unroll
                for (int t = 0; t < 4; t++) {
                    const int p = e1p[j + t];
                    const float base = (p < IN_BASE)
                        ? xr[p]
                        : e0v[p - IN_BASE] * xr[e0p[p - IN_BASE]];
                    v[t] = e1v[j + t] * base;
                }
            }
            bf16x4 o;
            o[0] = (__bf16)v[0]; o[1] = (__bf16)v[1];
            o[2] = (__bf16)v[2]; o[3] = (__bf16)v[3];
            *(bf16x4*)(xo + g * 4) = o;
        }
    }
}

// ---------------------------------------------------------------------------
// Kernel 2: per-bin accumulate -> bf16 W (writes every slot; no W memset)
// ---------------------------------------------------------------------------
__global__ void __launch_bounds__(512) accum_kernel(
    const float* __restrict__ segv, const unsigned short* __restrict__ segm,
    const unsigned char* __restrict__ segc,
    __bf16* __restrict__ Wb)
{
    __shared__ float Ws[BIN_ELEMS];                 // 69,632 B
    const int tid = threadIdx.x;
    const int b   = blockIdx.x;                     // bin 0..255

    for (int e = tid; e < BIN_ELEMS; e += 512) Ws[e] = 0.f;
    __syncthreads();

    for (int s = tid; s < NSEG; s += 512) {
        const int c    = segc[s * NBIN + b];
        const int base = (s * NBIN + b) * CAP;
        for (int j = 0; j < c; j++)
            atomicAdd(&Ws[segm[base + j]], segv[base + j]);
    }
    __syncthreads();

    __bf16* wo = Wb + (size_t)b * BIN_ELEMS;
    for (int e = tid; e < BIN_ELEMS / 4; e += 512) {
        bf16x4 o;
        o[0] = (__bf16)Ws[e * 4 + 0]; o[1] = (__bf16)Ws[e * 4 + 1];
        o[2] = (__bf16)Ws[e * 4 + 2]; o[3] = (__bf16)Ws[e * 4 + 3];
        *(bf16x4*)(wo + e * 4) = o;
    }
}

// ---------------------------------------------------------------------------
// Kernel 3: GEMM  C[M,N] = A[M,K] * W[N,K]^T + bias   (K-major, "NT")
//
// 256x256 tile, 8 waves (2M x 4N), wave tile 128x64, mfma_f32_32x32x16_bf16,
// BK=64, double-buffered LDS (128 KiB), 16B-chunk XOR swizzle (T2, global-
// side realization for global_load_lds).
//
// ROUND-7 RESTRUCTURE: ONE barrier per K-tile (was 8).  All 24 fragment
// reads of a tile target the same stable buffer, so the whole tile is one
// barrier-free scheduling region:
//   STAGE(t+1 -> other buf)  [8 gl_lds issued first, max time to fly]
//   RD a0,b0,b1 ; MFMA(0,0),(0,1) ; RD a1 ; MFMA(1,1),(1,0)
//     -- compiler emits fine-grained lgkmcnt(N), co-scheduling the 2304-cy
//        LDS drain with the 2048-cy MFMA stream (r3 model: serial before)
//   VMW(0) ; BAR   [depth-1 m97-style drain; loads had ~2500cy to land]
// Region safety: the staged buffer's last readers finished before the
// previous BAR; readers of the staged tile come after VMW(0)+BAR.
// setprio dropped (m190: neutral/negative on lockstep; would fence the
// interleave).  Register set unchanged from r5 (a[8]+b0[4]+b1[4], ~248/256).
// ---------------------------------------------------------------------------
#define BM 256
#define BN 256
#define BK 64
#define NKT (IN_TOT / BK)   // 34 K-tiles
static_assert(NKT % 2 == 0, "loop consumes K-tiles in pairs");

#define CFENCE asm volatile("" ::: "memory")
#define BAR do { CFENCE; __builtin_amdgcn_s_barrier(); CFENCE; } while (0)
#define VMW(n) asm volatile("s_waitcnt vmcnt(" #n ")" ::: "memory")
#define NOPS do {} while (0)

// stage one matrix-half (128 rows x 64 k) of K-tile `tile` into buffer `buf`
#define STAGE(G, SBC, buf, tile, half) do {                                     \
    const __bf16* _s = (G) + (size_t)((half) * 128) * IN_TOT + (tile) * 64;     \
    char* _d = (SBC) + (buf) * 32768 + (half) * 16384 + tid * 16;               \
    __builtin_amdgcn_global_load_lds((AS1 void*)(uintptr_t)_s,                  \
                                     (AS3 void*)_d, 16, 0, 0);                  \
    __builtin_amdgcn_global_load_lds((AS1 void*)(uintptr_t)(_s + (size_t)64 * IN_TOT), \
                                     (AS3 void*)(_d + 8192), 16, 0, 0);         \
} while (0)

// stage a full K-tile (A both halves + B both halves) = 8 gl_lds
#define STAGE_T(buf, tile) do {                                                 \
    STAGE(Ag, sAc, buf, tile, 0);                                               \
    STAGE(Ag, sAc, buf, tile, 1);                                               \
    STAGE(Wg, sBc, buf, tile, 0);                                               \
    STAGE(Wg, sBc, buf, tile, 1);                                               \
} while (0)

#define RD_A(pA, mq) do {                                                       \
    _Pragma("unroll") for (int ks = 0; ks < 4; ks++) {                          \
        const int kc = ks * 2 + khalf;                                          \
        _Pragma("unroll") for (int mi = 0; mi < 2; mi++) {                      \
            const int r = (mq) * 128 + wm * 64 + mi * 32 + l32;                 \
            a[mi * 4 + ks] = *(const bf16x8*)((pA) + r * 64 + ((kc ^ (r & 7)) * 8)); \
        }                                                                       \
    }                                                                           \
} while (0)

#define RD_B(pB, nq, barr) do {                                                 \
    _Pragma("unroll") for (int ks = 0; ks < 4; ks++) {                          \
        const int kc = ks * 2 + khalf;                                          \
        const int rb = (nq) * 128 + wn * 32 + l32;                              \
        barr[ks] = *(const bf16x8*)((pB) + rb * 64 + ((kc ^ (rb & 7)) * 8));    \
    }                                                                           \
} while (0)

// 8 MFMAs, no barriers, no setprio — free scheduling region
#define MMC(mq, nq, barr) do {                                                  \
    _Pragma("unroll") for (int mi = 0; mi < 2; mi++)                            \
        _Pragma("unroll") for (int ks = 0; ks < 4; ks++)                        \
            acc[mq][mi][nq] = __builtin_amdgcn_mfma_f32_32x32x16_bf16(          \
                a[mi * 4 + ks], barr[ks], acc[mq][mi][nq], 0, 0, 0);            \
} while (0)

// full K-tile compute from buffer `buf` (24 ds_read_b128 + 32 MFMA)
#define COMPUTE(buf) do {                                                       \
    const __bf16* _pA = sA + (buf) * 16384;                                     \
    const __bf16* _pB = sB + (buf) * 16384;                                     \
    RD_A(_pA, 0); RD_B(_pB, 0, b0); RD_B(_pB, 1, b1);                           \
    MMC(0, 0, b0); MMC(0, 1, b1);                                               \
    RD_A(_pA, 1);                                                               \
    MMC(1, 1, b1); MMC(1, 0, b0);                                               \
} while (0)

__global__ void __launch_bounds__(512, 2) gemm_kernel(
    const __bf16* __restrict__ A,   // [BATCH][IN_TOT]
    const __bf16* __restrict__ W,   // [OUT_F][IN_TOT]
    const float*  __restrict__ bias,
    float* __restrict__ C)          // [BATCH][OUT_F]
{
    __shared__ __align__(16) __bf16 sA[2 * 256 * 64];   // 64 KiB (2 bufs)
    __shared__ __align__(16) __bf16 sB[2 * 256 * 64];   // 64 KiB

    const int tid   = threadIdx.x;
    const int bm    = blockIdx.x;    // M tile (32)
    const int bn    = blockIdx.y;    // N tile (8)
    const int wave  = tid >> 6;
    const int lane  = tid & 63;
    const int wm    = wave >> 2;     // 0..1
    const int wn    = wave & 3;      // 0..3
    const int l32   = lane & 31;
    const int khalf = lane >> 5;

    floatx16 acc[2][2][2] = {};      // [m quadrant][mi (32-row)][n quadrant]
    bf16x8 a[8];                     // A-frag cache (current m-quadrant)
    bf16x8 b0[4], b1[4];             // B-frag caches for n-quadrant 0 / 1

    // staging: thread t -> row = t>>3 (x2 at +64), slot = t&7.
    // slot s of row r holds global chunk s ^ (r&7) => fetch chunk (t&7)^((t>>3)&7)
    const int srow   = tid >> 3;
    const int kchunk = ((tid & 7) ^ ((tid >> 3) & 7)) * 8;
    const __bf16* Ag = A + (size_t)(bm * BM + srow) * IN_TOT + kchunk;
    const __bf16* Wg = W + (size_t)(bn * BN + srow) * IN_TOT + kchunk;
    char* sAc = (char*)sA;
    char* sBc = (char*)sB;

    // prologue: tile0 -> buf0
    STAGE_T(0, 0);
    VMW(0);
    BAR;

#pragma unroll 1
    for (int i = 0; i < NKT / 2 - 1; ++i) {        // 16 iters: tiles 0..31
        STAGE_T(1, 2 * i + 1);
        COMPUTE(0);
        VMW(0);
        BAR;
        STAGE_T(0, 2 * i + 2);
        COMPUTE(1);
        VMW(0);
        BAR;
    }
    // tail: buf0 = tile 32
    STAGE_T(1, NKT - 1);
    COMPUTE(0);
    VMW(0);
    BAR;
    COMPUTE(1);

    // epilogue: C/D col = lane&31, row = (reg&3) + 8*(reg>>2) + 4*khalf  [verified]
#pragma unroll
    for (int m = 0; m < 2; m++)
#pragma unroll
    for (int mi = 0; mi < 2; mi++)
#pragma unroll
    for (int n = 0; n < 2; n++) {
        const int colg = bn * BN + n * 128 + wn * 32 + l32;
        const float bvv = bias[colg];
        const int rowb = bm * BM + m * 128 + wm * 64 + mi * 32 + 4 * khalf;
#pragma unroll
        for (int reg = 0; reg < 16; reg++) {
            const int rowg = rowb + (reg & 3) + 8 * (reg >> 2);
            C[(size_t)rowg * OUT_F + colg] = acc[m][mi][n][reg] + bvv;
        }
    }
}

// ---------------------------------------------------------------------------
// Launch
// ---------------------------------------------------------------------------
extern "C" void kernel_launch(void* const* d_in, const int* in_sizes, int n_in,
                              void* d_out, int out_size, void* d_ws, size_t ws_size,
                              hipStream_t stream) {
    const float* x      = (const float*)d_in[0];
    const float* w_vals = (const float*)d_in[1];
    const int*   w_rows = (const int*)  d_in[2];
    const int*   w_cols = (const int*)  d_in[3];
    const float* b_vals = (const float*)d_in[4];
    const int*   b_idx  = (const int*)  d_in[5];
    const float* e0v    = (const float*)d_in[6];
    const int*   e0p    = (const int*)  d_in[7];
    const float* e1v    = (const float*)d_in[8];
    const int*   e1p    = (const int*)  d_in[9];
    float* out = (float*)d_out;

    // workspace: Wb | bfp | xb | segv | segm | segc   (~59.1 MB)
    char* ws = (char*)d_ws;
    const size_t W_BF16_BYTES = (size_t)OUT_F * IN_TOT * 2;      //  8,912,896
    const size_t B_F32_BYTES  = (size_t)OUT_F * 4;               //      8,192
    const size_t XB_BYTES     = (size_t)BATCH * IN_TOT * 2;      // 35,651,584
    const size_t SEGV_BYTES   = (size_t)NSEG * NBIN * CAP * 4;   //  9,609,216
    const size_t SEGM_BYTES   = (size_t)NSEG * NBIN * CAP * 2;   //  4,804,608
    __bf16*         Wb   = (__bf16*)ws;
    float*          bfp  = (float*)(ws + W_BF16_BYTES);
    __bf16*         xb   = (__bf16*)(ws + W_BF16_BYTES + B_F32_BYTES);
    float*          segv = (float*)(ws + W_BF16_BYTES + B_F32_BYTES + XB_BYTES);
    unsigned short* segm = (unsigned short*)((char*)segv + SEGV_BYTES);
    unsigned char*  segc = (unsigned char*)((char*)segm + SEGM_BYTES);

    // only the bias accumulator needs zeroing (8 KB)
    hipMemsetAsync(bfp, 0, B_F32_BYTES, stream);

    prep_kernel<<<NB_SCAT + NB_BIAS + NB_BUILD, 512, 0, stream>>>(
        x, e0v, e0p, e1v, e1p, xb,
        w_vals, w_rows, w_cols, b_vals, b_idx,
        segv, segm, segc, bfp);

    accum_kernel<<<NBIN, 512, 0, stream>>>(segv, segm, segc, Wb);

    dim3 grid(BATCH / BM, OUT_F / BN);
    gemm_kernel<<<grid, 512, 0, stream>>>(xb, Wb, bfp, out);
}